// Round 6
// baseline (204.959 us; speedup 1.0000x reference)
//
#include <hip/hip_runtime.h>

#define N_DIM 16384
#define C_DIM 10000
#define D_DIM 128
#define CT 79            // c-tiles of 128 (ceil(10000/128))
#define C_PAD 10240      // mu rows padded/zeroed by prep
#define BM 64            // z rows per block tile
#define BN 128           // mu rows per block tile
#define MT 256           // 16384/64 m-tiles
#define ZPB 2048         // z prep blocks  (8 rows each)
#define MPB 1280         // mu prep blocks (8 rows each)

typedef __attribute__((ext_vector_type(8))) short bf16x8;
typedef __attribute__((ext_vector_type(4))) float f32x4;
typedef __attribute__((ext_vector_type(2))) unsigned int uint2v;

static __device__ __forceinline__ unsigned short f2bf(float x) {
  unsigned int u = __float_as_uint(x);
  u += 0x7fffu + ((u >> 16) & 1u);   // round-to-nearest-even
  return (unsigned short)(u >> 16);
}

// --- fused prep, one dispatch (identical to the verified R1/R5 version).
// z  -> bf16 LINEAR, pre-scaled by iv=exp(-lc); atbl[n] = -0.5*||z||^2*iv
// mu -> bf16 PRE-SWIZZLED (byte col ^= (row&7)<<4) for main's linear
//       global_load_lds staging (both-sides-or-neither, G21);
//       btbl[c] (lse added in main). last block: lse = logsumexp(prior)
__global__ __launch_bounds__(256) void prep_kernel(
    const float* __restrict__ z, const float* __restrict__ mu,
    const float* __restrict__ log_cov, const float* __restrict__ prior,
    unsigned short* __restrict__ zb, unsigned short* __restrict__ mub,
    float* __restrict__ atbl, float* __restrict__ btbl, float* __restrict__ lse_out) {
  const int bid = blockIdx.x;
  const int tid = threadIdx.x;
  if (bid < ZPB + MPB) {
    const bool isz = bid < ZPB;
    const int lane = tid & 63;
    const int row = (isz ? bid : bid - ZPB) * 8 + ((tid >> 6) << 1) + (lane >> 5);
    const int col = (lane & 31) * 4;      // float index within row
    const int nrows = isz ? N_DIM : C_DIM;
    f32x4 v = {0.f, 0.f, 0.f, 0.f};
    if (row < nrows)
      v = *(const f32x4*)((isz ? z : mu) + (size_t)row * D_DIM + col);
    float ss = v[0]*v[0] + v[1]*v[1] + v[2]*v[2] + v[3]*v[3];
    #pragma unroll
    for (int off = 16; off; off >>= 1) ss += __shfl_down(ss, off, 32);
    float lc = log_cov[0];
    float iv = expf(-lc);
    if (isz) { v[0]*=iv; v[1]*=iv; v[2]*=iv; v[3]*=iv; }   // fold iv into z
    uint2v packed;
    packed[0] = (unsigned int)f2bf(v[0]) | ((unsigned int)f2bf(v[1]) << 16);
    packed[1] = (unsigned int)f2bf(v[2]) | ((unsigned int)f2bf(v[3]) << 16);
    int cb = (lane & 31) * 8;             // byte col of this 8B chunk
    if (isz) {
      *(uint2v*)((char*)zb + (size_t)row * 256 + cb) = packed;               // linear
    } else {
      *(uint2v*)((char*)mub + (size_t)row * 256 + (cb ^ ((row & 7) << 4))) = packed;
    }
    if ((lane & 31) == 0) {
      if (isz) {
        atbl[row] = -0.5f * ss * iv;
      } else {
        btbl[row] = (row < C_DIM)
            ? (prior[row] - 0.5f * ss * iv - 0.5f * (float)D_DIM * lc) : 0.f;
      }
    }
  } else {
    __shared__ float red[256];
    const f32x4* p4 = (const f32x4*)prior;
    float m = -1e30f;
    for (int i = tid; i < C_DIM / 4; i += 256) {
      f32x4 v = p4[i];
      m = fmaxf(fmaxf(fmaxf(m, v[0]), fmaxf(v[1], v[2])), v[3]);
    }
    red[tid] = m; __syncthreads();
    for (int s = 128; s; s >>= 1) {
      if (tid < s) red[tid] = fmaxf(red[tid], red[tid + s]);
      __syncthreads();
    }
    float mx = red[0]; __syncthreads();
    float sum = 0.f;
    for (int i = tid; i < C_DIM / 4; i += 256) {
      f32x4 v = p4[i];
      sum += expf(v[0] - mx) + expf(v[1] - mx) + expf(v[2] - mx) + expf(v[3] - mx);
    }
    red[tid] = sum; __syncthreads();
    for (int s = 128; s; s >>= 1) {
      if (tid < s) red[tid] += red[tid + s];
      __syncthreads();
    }
    if (tid == 0) *lse_out = mx + logf(red[0]);
  }
}

// --- main: verified R5 structure (64m x 128c tile, LDS mu staging, LDS
// transpose epilogue with 512B store runs, 5 blocks/CU), with ONE change:
// plain cached stores instead of nontemporal. NT (L2 no-allocate) was pushing
// ~128B quanta toward HBM from 1280 concurrent 40KB-strided writers; plain
// write-back lets L2 aggregate dirty lines and evict in large sequential
// bursts (the fill kernel's regime). Stores are full-line (each half-wave
// covers 4 complete 128B lines), so no write-allocate read traffic.
__global__ __launch_bounds__(256, 5) void lda_main_kernel(
    const unsigned short* __restrict__ zb, const unsigned short* __restrict__ mub,
    const float* __restrict__ atbl, const float* __restrict__ btbl,
    const float* __restrict__ lse_p, const float* __restrict__ log_cov,
    float* __restrict__ out) {
  __shared__ char lds[BN * 256];      // 32 KB (mu tile; later 64x128 f32 out tile)

  const int ct = blockIdx.x;          // 0..78
  const int mt = blockIdx.y;          // 0..255
  const int tid = threadIdx.x;
  const int rbase = mt * BM;
  const int cbase = ct * BN;
  const int wid = tid >> 6;
  const int lane = tid & 63;
  const int l15 = lane & 15;
  const int lq = lane >> 4;

  // stage mu tile: 8 issues x 1KB per wave, linear dest (global pre-swizzled)
  {
    const char* gm = (const char*)mub + (size_t)cbase * 256 + wid * 8192 + lane * 16;
    char* lm = lds + wid * 8192;
    #pragma unroll
    for (int it = 0; it < 8; ++it)
      __builtin_amdgcn_global_load_lds(
          (const __attribute__((address_space(1))) void*)(gm + it * 1024),
          (__attribute__((address_space(3))) void*)(lm + it * 1024), 16, 0, 0);
  }

  // z fragments from global (16KB slab; L1/L2-resident across the block's waves)
  const int zrow = rbase + wid * 16 + l15;     // this lane's z row (MFMA N=col=l15)
  bf16x8 zf[4];
  #pragma unroll
  for (int kk = 0; kk < 4; ++kk)
    zf[kk] = *(const bf16x8*)((const char*)zb + (size_t)zrow * 256 + kk * 64 + lq * 16);

  // per-lane c-terms for the store phase: c = cbase + (lane&31)*4 .. +3
  const int l31 = lane & 31;
  const float lse = lse_p[0];
  f32x4 btv = *(const f32x4*)&btbl[cbase + l31 * 4];
  btv[0] -= lse; btv[1] -= lse; btv[2] -= lse; btv[3] -= lse;

  __syncthreads();    // mu staged

  // MFMA: acc[a] over 8 c-fragments; A=mu (M=c), B=z (N=m).
  // mf loads paired with their MFMAs to cap live mu fragments at 2 (8 VGPR),
  // keeping total allocation under the 102-VGPR / 5-blocks-per-CU budget.
  f32x4 acc[8] = {};
  #pragma unroll
  for (int kk = 0; kk < 4; ++kk) {
    const int kbyte = kk * 64 + lq * 16;
    #pragma unroll
    for (int a = 0; a < 8; a += 2) {
      int r0 = a * 16 + l15;
      int r1 = (a + 1) * 16 + l15;
      bf16x8 m0 = *(const bf16x8*)(lds + r0 * 256 + (kbyte ^ ((r0 & 7) << 4)));
      bf16x8 m1 = *(const bf16x8*)(lds + r1 * 256 + (kbyte ^ ((r1 & 7) << 4)));
      acc[a]     = __builtin_amdgcn_mfma_f32_16x16x32_bf16(m0, zf[kk], acc[a],     0, 0, 0);
      acc[a + 1] = __builtin_amdgcn_mfma_f32_16x16x32_bf16(m1, zf[kk], acc[a + 1], 0, 0, 0);
    }
  }

  __syncthreads();    // all waves done reading mu; LDS becomes the output tile

  // write fragments -> LDS [m][c] (fp32, 512B rows, XOR-swizzled to kill the
  // 512B-stride write conflict)
  const int mloc = wid * 16 + l15;    // this lane's m row (D col = l15)
  #pragma unroll
  for (int a = 0; a < 8; ++a) {
    int cb4 = (a * 16 + lq * 4) * 4;  // byte col in the 512B row
    *(f32x4*)(lds + mloc * 512 + (cb4 ^ ((mloc & 7) << 4))) = acc[a];
  }

  // read back row-major (own rows only -- no barrier), 2 rows per instruction,
  // and store 512B contiguous per half-wave (plain cached stores: let L2
  // write-back aggregate into sequential HBM bursts)
  const int hl = lane >> 5;
  #pragma unroll
  for (int i = 0; i < 16; i += 2) {
    int m = wid * 16 + i + hl;
    int rowg = rbase + m;
    f32x4 t = *(const f32x4*)(lds + m * 512 + ((l31 * 16) ^ ((m & 7) << 4)));
    float av = atbl[rowg];
    int cg = cbase + l31 * 4;
    if (cg < C_DIM) {                 // divergent only in the last c-tile
      f32x4 v;
      #pragma unroll
      for (int r = 0; r < 4; ++r) v[r] = av + btv[r] + t[r];
      *(f32x4*)(out + (size_t)rowg * C_DIM + cg) = v;
    }
  }
}

extern "C" void kernel_launch(void* const* d_in, const int* in_sizes, int n_in,
                              void* d_out, int out_size, void* d_ws, size_t ws_size,
                              hipStream_t stream) {
  const float* z     = (const float*)d_in[0];
  const float* mu    = (const float*)d_in[1];
  const float* lcov  = (const float*)d_in[2];
  const float* prior = (const float*)d_in[3];
  float* out = (float*)d_out;

  char* w = (char*)d_ws;
  unsigned short* zb  = (unsigned short*)w;                       // 4,194,304 B
  unsigned short* mub = (unsigned short*)(w + 4194304);           // 2,621,440 B
  float* atbl = (float*)(w + 4194304 + 2621440);                  // 65,536 B
  float* btbl = atbl + N_DIM;                                     // 40,960 B
  float* lse  = btbl + C_PAD;                                     // 4 B

  prep_kernel<<<ZPB + MPB + 1, 256, 0, stream>>>(z, mu, lcov, prior,
                                                 zb, mub, atbl, btbl, lse);
  dim3 grid(CT, MT);   // 79 x 256 = 20224 tiles
  lda_main_kernel<<<grid, 256, 0, stream>>>(zb, mub, atbl, btbl, lse, lcov, out);
}

// Round 7
// 143.205 us; speedup vs baseline: 1.4312x; 1.4312x over previous
//
#include <hip/hip_runtime.h>

#define N_DIM 16384
#define C_DIM 10000
#define D_DIM 128
#define CT 79            // c-tiles of 128 (ceil(10000/128))
#define C_PAD 10240      // mu rows padded/zeroed by prep
#define BM 64            // z rows per block tile
#define BN 128           // mu rows per block tile
#define MT 256           // 16384/64 m-tiles
#define NWG (CT * MT)    // 20224 blocks; 20224 % 8 == 0 -> bijective XCD swizzle
#define WPX (NWG / 8)    // 2528 blocks per XCD
#define ZPB 2048         // z prep blocks  (8 rows each)
#define MPB 1280         // mu prep blocks (8 rows each)

typedef __attribute__((ext_vector_type(8))) short bf16x8;
typedef __attribute__((ext_vector_type(4))) float f32x4;
typedef __attribute__((ext_vector_type(2))) unsigned int uint2v;

static __device__ __forceinline__ unsigned short f2bf(float x) {
  unsigned int u = __float_as_uint(x);
  u += 0x7fffu + ((u >> 16) & 1u);   // round-to-nearest-even
  return (unsigned short)(u >> 16);
}

// --- fused prep, one dispatch (identical to the verified R1/R5 version).
// z  -> bf16 LINEAR, pre-scaled by iv=exp(-lc); atbl[n] = -0.5*||z||^2*iv
// mu -> bf16 PRE-SWIZZLED (byte col ^= (row&7)<<4) for main's linear
//       global_load_lds staging (both-sides-or-neither, G21);
//       btbl[c] (lse added in main). last block: lse = logsumexp(prior)
__global__ __launch_bounds__(256) void prep_kernel(
    const float* __restrict__ z, const float* __restrict__ mu,
    const float* __restrict__ log_cov, const float* __restrict__ prior,
    unsigned short* __restrict__ zb, unsigned short* __restrict__ mub,
    float* __restrict__ atbl, float* __restrict__ btbl, float* __restrict__ lse_out) {
  const int bid = blockIdx.x;
  const int tid = threadIdx.x;
  if (bid < ZPB + MPB) {
    const bool isz = bid < ZPB;
    const int lane = tid & 63;
    const int row = (isz ? bid : bid - ZPB) * 8 + ((tid >> 6) << 1) + (lane >> 5);
    const int col = (lane & 31) * 4;      // float index within row
    const int nrows = isz ? N_DIM : C_DIM;
    f32x4 v = {0.f, 0.f, 0.f, 0.f};
    if (row < nrows)
      v = *(const f32x4*)((isz ? z : mu) + (size_t)row * D_DIM + col);
    float ss = v[0]*v[0] + v[1]*v[1] + v[2]*v[2] + v[3]*v[3];
    #pragma unroll
    for (int off = 16; off; off >>= 1) ss += __shfl_down(ss, off, 32);
    float lc = log_cov[0];
    float iv = expf(-lc);
    if (isz) { v[0]*=iv; v[1]*=iv; v[2]*=iv; v[3]*=iv; }   // fold iv into z
    uint2v packed;
    packed[0] = (unsigned int)f2bf(v[0]) | ((unsigned int)f2bf(v[1]) << 16);
    packed[1] = (unsigned int)f2bf(v[2]) | ((unsigned int)f2bf(v[3]) << 16);
    int cb = (lane & 31) * 8;             // byte col of this 8B chunk
    if (isz) {
      *(uint2v*)((char*)zb + (size_t)row * 256 + cb) = packed;               // linear
    } else {
      *(uint2v*)((char*)mub + (size_t)row * 256 + (cb ^ ((row & 7) << 4))) = packed;
    }
    if ((lane & 31) == 0) {
      if (isz) {
        atbl[row] = -0.5f * ss * iv;
      } else {
        btbl[row] = (row < C_DIM)
            ? (prior[row] - 0.5f * ss * iv - 0.5f * (float)D_DIM * lc) : 0.f;
      }
    }
  } else {
    __shared__ float red[256];
    const f32x4* p4 = (const f32x4*)prior;
    float m = -1e30f;
    for (int i = tid; i < C_DIM / 4; i += 256) {
      f32x4 v = p4[i];
      m = fmaxf(fmaxf(fmaxf(m, v[0]), fmaxf(v[1], v[2])), v[3]);
    }
    red[tid] = m; __syncthreads();
    for (int s = 128; s; s >>= 1) {
      if (tid < s) red[tid] = fmaxf(red[tid], red[tid + s]);
      __syncthreads();
    }
    float mx = red[0]; __syncthreads();
    float sum = 0.f;
    for (int i = tid; i < C_DIM / 4; i += 256) {
      f32x4 v = p4[i];
      sum += expf(v[0] - mx) + expf(v[1] - mx) + expf(v[2] - mx) + expf(v[3] - mx);
    }
    red[tid] = sum; __syncthreads();
    for (int s = 128; s; s >>= 1) {
      if (tid < s) red[tid] += red[tid + s];
      __syncthreads();
    }
    if (tid == 0) *lse_out = mx + logf(red[0]);
  }
}

// --- main: verified R5 structure (64m x 128c tile, LDS mu staging, paired-mf
// MFMA loop, LDS transpose epilogue, NT 512B store runs, 5 blocks/CU) plus
// ONE change: XCD-aware block swizzle (T1, bijective: NWG%8==0). Each XCD
// gets a contiguous 2528-block chunk enumerated ct-fastest, so it owns a
// contiguous 2048-row (82 MB) output region and its resident blocks sweep
// ~2 full 2.6MB row-strips densely -> NT write streams per memory channel
// stay page-local instead of interleaving 8 XCDs' scattered 512B runs.
// Side effect: each XCD's z reads shrink to a private 512KB slab (L2-local).
__global__ __launch_bounds__(256, 5) void lda_main_kernel(
    const unsigned short* __restrict__ zb, const unsigned short* __restrict__ mub,
    const float* __restrict__ atbl, const float* __restrict__ btbl,
    const float* __restrict__ lse_p, const float* __restrict__ log_cov,
    float* __restrict__ out) {
  __shared__ char lds[BN * 256];      // 32 KB (mu tile; later 64x128 f32 out tile)

  // XCD swizzle: lin%8 = this block's XCD (round-robin dispatch); give XCD k
  // the contiguous work chunk [k*WPX, (k+1)*WPX), enumerated ct-fastest.
  const int lin = blockIdx.x + CT * blockIdx.y;
  const int newlin = (lin & 7) * WPX + (lin >> 3);
  const int ct = newlin % CT;         // 0..78
  const int mt = newlin / CT;         // 0..255

  const int tid = threadIdx.x;
  const int rbase = mt * BM;
  const int cbase = ct * BN;
  const int wid = tid >> 6;
  const int lane = tid & 63;
  const int l15 = lane & 15;
  const int lq = lane >> 4;

  // stage mu tile: 8 issues x 1KB per wave, linear dest (global pre-swizzled)
  {
    const char* gm = (const char*)mub + (size_t)cbase * 256 + wid * 8192 + lane * 16;
    char* lm = lds + wid * 8192;
    #pragma unroll
    for (int it = 0; it < 8; ++it)
      __builtin_amdgcn_global_load_lds(
          (const __attribute__((address_space(1))) void*)(gm + it * 1024),
          (__attribute__((address_space(3))) void*)(lm + it * 1024), 16, 0, 0);
  }

  // z fragments from global (16KB slab; L1/L2-resident across the block's waves)
  const int zrow = rbase + wid * 16 + l15;     // this lane's z row (MFMA N=col=l15)
  bf16x8 zf[4];
  #pragma unroll
  for (int kk = 0; kk < 4; ++kk)
    zf[kk] = *(const bf16x8*)((const char*)zb + (size_t)zrow * 256 + kk * 64 + lq * 16);

  // per-lane c-terms for the store phase: c = cbase + (lane&31)*4 .. +3
  const int l31 = lane & 31;
  const float lse = lse_p[0];
  f32x4 btv = *(const f32x4*)&btbl[cbase + l31 * 4];
  btv[0] -= lse; btv[1] -= lse; btv[2] -= lse; btv[3] -= lse;

  __syncthreads();    // mu staged

  // MFMA: acc[a] over 8 c-fragments; A=mu (M=c), B=z (N=m).
  // mf loads paired with their MFMAs to cap live mu fragments at 2 (8 VGPR),
  // keeping total allocation under the 102-VGPR / 5-blocks-per-CU budget.
  f32x4 acc[8] = {};
  #pragma unroll
  for (int kk = 0; kk < 4; ++kk) {
    const int kbyte = kk * 64 + lq * 16;
    #pragma unroll
    for (int a = 0; a < 8; a += 2) {
      int r0 = a * 16 + l15;
      int r1 = (a + 1) * 16 + l15;
      bf16x8 m0 = *(const bf16x8*)(lds + r0 * 256 + (kbyte ^ ((r0 & 7) << 4)));
      bf16x8 m1 = *(const bf16x8*)(lds + r1 * 256 + (kbyte ^ ((r1 & 7) << 4)));
      acc[a]     = __builtin_amdgcn_mfma_f32_16x16x32_bf16(m0, zf[kk], acc[a],     0, 0, 0);
      acc[a + 1] = __builtin_amdgcn_mfma_f32_16x16x32_bf16(m1, zf[kk], acc[a + 1], 0, 0, 0);
    }
  }

  __syncthreads();    // all waves done reading mu; LDS becomes the output tile

  // write fragments -> LDS [m][c] (fp32, 512B rows, XOR-swizzled to kill the
  // 512B-stride write conflict)
  const int mloc = wid * 16 + l15;    // this lane's m row (D col = l15)
  #pragma unroll
  for (int a = 0; a < 8; ++a) {
    int cb4 = (a * 16 + lq * 4) * 4;  // byte col in the 512B row
    *(f32x4*)(lds + mloc * 512 + (cb4 ^ ((mloc & 7) << 4))) = acc[a];
  }

  // read back row-major (own rows only -- no barrier), 2 rows per instruction,
  // and store 512B contiguous per half-wave (nontemporal -- verified R6:
  // cached stores regress 127->205; NT's in-order stream is load-bearing)
  const int hl = lane >> 5;
  #pragma unroll
  for (int i = 0; i < 16; i += 2) {
    int m = wid * 16 + i + hl;
    int rowg = rbase + m;
    f32x4 t = *(const f32x4*)(lds + m * 512 + ((l31 * 16) ^ ((m & 7) << 4)));
    float av = atbl[rowg];
    int cg = cbase + l31 * 4;
    if (cg < C_DIM) {                 // divergent only in the last c-tile
      f32x4 v;
      #pragma unroll
      for (int r = 0; r < 4; ++r) v[r] = av + btv[r] + t[r];
      __builtin_nontemporal_store(v, (f32x4*)(out + (size_t)rowg * C_DIM + cg));
    }
  }
}

extern "C" void kernel_launch(void* const* d_in, const int* in_sizes, int n_in,
                              void* d_out, int out_size, void* d_ws, size_t ws_size,
                              hipStream_t stream) {
  const float* z     = (const float*)d_in[0];
  const float* mu    = (const float*)d_in[1];
  const float* lcov  = (const float*)d_in[2];
  const float* prior = (const float*)d_in[3];
  float* out = (float*)d_out;

  char* w = (char*)d_ws;
  unsigned short* zb  = (unsigned short*)w;                       // 4,194,304 B
  unsigned short* mub = (unsigned short*)(w + 4194304);           // 2,621,440 B
  float* atbl = (float*)(w + 4194304 + 2621440);                  // 65,536 B
  float* btbl = atbl + N_DIM;                                     // 40,960 B
  float* lse  = btbl + C_PAD;                                     // 4 B

  prep_kernel<<<ZPB + MPB + 1, 256, 0, stream>>>(z, mu, lcov, prior,
                                                 zb, mub, atbl, btbl, lse);
  dim3 grid(CT, MT);   // 79 x 256 = 20224 tiles (swizzled inside the kernel)
  lda_main_kernel<<<grid, 256, 0, stream>>>(zb, mub, atbl, btbl, lse, lcov, out);
}

// Round 8
// 128.867 us; speedup vs baseline: 1.5905x; 1.1113x over previous
//
#include <hip/hip_runtime.h>

#define N_DIM 16384
#define C_DIM 10000
#define D_DIM 128
#define CT 79            // c-tiles of 128 (ceil(10000/128))
#define C_PAD 10240      // mu rows padded/zeroed by prep
#define BM 64            // z rows per block tile
#define BN 128           // mu rows per block tile
#define MT 256           // 16384/64 m-tiles
#define ZPB 2048         // z prep blocks  (8 rows each)
#define MPB 1280         // mu prep blocks (8 rows each)

typedef __attribute__((ext_vector_type(8))) short bf16x8;
typedef __attribute__((ext_vector_type(4))) float f32x4;
typedef __attribute__((ext_vector_type(2))) unsigned int uint2v;

static __device__ __forceinline__ unsigned short f2bf(float x) {
  unsigned int u = __float_as_uint(x);
  u += 0x7fffu + ((u >> 16) & 1u);   // round-to-nearest-even
  return (unsigned short)(u >> 16);
}

// --- fused prep, one dispatch (identical to the verified R1/R5 version).
// z  -> bf16 LINEAR, pre-scaled by iv=exp(-lc); atbl[n] = -0.5*||z||^2*iv
// mu -> bf16 PRE-SWIZZLED (byte col ^= (row&7)<<4) for main's linear
//       global_load_lds staging (both-sides-or-neither, G21);
//       btbl[c] (lse added in main). last block: lse = logsumexp(prior)
__global__ __launch_bounds__(256) void prep_kernel(
    const float* __restrict__ z, const float* __restrict__ mu,
    const float* __restrict__ log_cov, const float* __restrict__ prior,
    unsigned short* __restrict__ zb, unsigned short* __restrict__ mub,
    float* __restrict__ atbl, float* __restrict__ btbl, float* __restrict__ lse_out) {
  const int bid = blockIdx.x;
  const int tid = threadIdx.x;
  if (bid < ZPB + MPB) {
    const bool isz = bid < ZPB;
    const int lane = tid & 63;
    const int row = (isz ? bid : bid - ZPB) * 8 + ((tid >> 6) << 1) + (lane >> 5);
    const int col = (lane & 31) * 4;      // float index within row
    const int nrows = isz ? N_DIM : C_DIM;
    f32x4 v = {0.f, 0.f, 0.f, 0.f};
    if (row < nrows)
      v = *(const f32x4*)((isz ? z : mu) + (size_t)row * D_DIM + col);
    float ss = v[0]*v[0] + v[1]*v[1] + v[2]*v[2] + v[3]*v[3];
    #pragma unroll
    for (int off = 16; off; off >>= 1) ss += __shfl_down(ss, off, 32);
    float lc = log_cov[0];
    float iv = expf(-lc);
    if (isz) { v[0]*=iv; v[1]*=iv; v[2]*=iv; v[3]*=iv; }   // fold iv into z
    uint2v packed;
    packed[0] = (unsigned int)f2bf(v[0]) | ((unsigned int)f2bf(v[1]) << 16);
    packed[1] = (unsigned int)f2bf(v[2]) | ((unsigned int)f2bf(v[3]) << 16);
    int cb = (lane & 31) * 8;             // byte col of this 8B chunk
    if (isz) {
      *(uint2v*)((char*)zb + (size_t)row * 256 + cb) = packed;               // linear
    } else {
      *(uint2v*)((char*)mub + (size_t)row * 256 + (cb ^ ((row & 7) << 4))) = packed;
    }
    if ((lane & 31) == 0) {
      if (isz) {
        atbl[row] = -0.5f * ss * iv;
      } else {
        btbl[row] = (row < C_DIM)
            ? (prior[row] - 0.5f * ss * iv - 0.5f * (float)D_DIM * lc) : 0.f;
      }
    }
  } else {
    __shared__ float red[256];
    const f32x4* p4 = (const f32x4*)prior;
    float m = -1e30f;
    for (int i = tid; i < C_DIM / 4; i += 256) {
      f32x4 v = p4[i];
      m = fmaxf(fmaxf(fmaxf(m, v[0]), fmaxf(v[1], v[2])), v[3]);
    }
    red[tid] = m; __syncthreads();
    for (int s = 128; s; s >>= 1) {
      if (tid < s) red[tid] = fmaxf(red[tid], red[tid + s]);
      __syncthreads();
    }
    float mx = red[0]; __syncthreads();
    float sum = 0.f;
    for (int i = tid; i < C_DIM / 4; i += 256) {
      f32x4 v = p4[i];
      sum += expf(v[0] - mx) + expf(v[1] - mx) + expf(v[2] - mx) + expf(v[3] - mx);
    }
    red[tid] = sum; __syncthreads();
    for (int s = 128; s; s >>= 1) {
      if (tid < s) red[tid] += red[tid + s];
      __syncthreads();
    }
    if (tid == 0) *lse_out = mx + logf(red[0]);
  }
}

// --- main: verified R5 structure (64m x 128c tile, default block order --
// XCD chunking regressed 127->143 in R7 -- LDS mu staging, paired-mf MFMA
// loop, LDS transpose epilogue, NT 512B store runs, 5 blocks/CU), with the
// epilogue BATCHED: all 8 LDS reads + 8 atbl loads complete first, then the
// 8 NT stores issue back-to-back (dense store burst instead of a
// ds_read-latency-spaced chain). acc[] is dead by the epilogue, so t[8]+av[8]
// fit the 102-VGPR / 5-blocks-per-CU budget.
__global__ __launch_bounds__(256, 5) void lda_main_kernel(
    const unsigned short* __restrict__ zb, const unsigned short* __restrict__ mub,
    const float* __restrict__ atbl, const float* __restrict__ btbl,
    const float* __restrict__ lse_p, const float* __restrict__ log_cov,
    float* __restrict__ out) {
  __shared__ char lds[BN * 256];      // 32 KB (mu tile; later 64x128 f32 out tile)

  const int ct = blockIdx.x;          // 0..78
  const int mt = blockIdx.y;          // 0..255
  const int tid = threadIdx.x;
  const int rbase = mt * BM;
  const int cbase = ct * BN;
  const int wid = tid >> 6;
  const int lane = tid & 63;
  const int l15 = lane & 15;
  const int lq = lane >> 4;

  // stage mu tile: 8 issues x 1KB per wave, linear dest (global pre-swizzled)
  {
    const char* gm = (const char*)mub + (size_t)cbase * 256 + wid * 8192 + lane * 16;
    char* lm = lds + wid * 8192;
    #pragma unroll
    for (int it = 0; it < 8; ++it)
      __builtin_amdgcn_global_load_lds(
          (const __attribute__((address_space(1))) void*)(gm + it * 1024),
          (__attribute__((address_space(3))) void*)(lm + it * 1024), 16, 0, 0);
  }

  // z fragments from global (16KB slab; L1/L2-resident across the block's waves)
  const int zrow = rbase + wid * 16 + l15;     // this lane's z row (MFMA N=col=l15)
  bf16x8 zf[4];
  #pragma unroll
  for (int kk = 0; kk < 4; ++kk)
    zf[kk] = *(const bf16x8*)((const char*)zb + (size_t)zrow * 256 + kk * 64 + lq * 16);

  // per-lane c-terms for the store phase: c = cbase + (lane&31)*4 .. +3
  const int l31 = lane & 31;
  const float lse = lse_p[0];
  f32x4 btv = *(const f32x4*)&btbl[cbase + l31 * 4];
  btv[0] -= lse; btv[1] -= lse; btv[2] -= lse; btv[3] -= lse;

  __syncthreads();    // mu staged

  // MFMA: acc[a] over 8 c-fragments; A=mu (M=c), B=z (N=m).
  // mf loads paired with their MFMAs to cap live mu fragments at 2 (8 VGPR),
  // keeping total allocation under the 102-VGPR / 5-blocks-per-CU budget.
  f32x4 acc[8] = {};
  #pragma unroll
  for (int kk = 0; kk < 4; ++kk) {
    const int kbyte = kk * 64 + lq * 16;
    #pragma unroll
    for (int a = 0; a < 8; a += 2) {
      int r0 = a * 16 + l15;
      int r1 = (a + 1) * 16 + l15;
      bf16x8 m0 = *(const bf16x8*)(lds + r0 * 256 + (kbyte ^ ((r0 & 7) << 4)));
      bf16x8 m1 = *(const bf16x8*)(lds + r1 * 256 + (kbyte ^ ((r1 & 7) << 4)));
      acc[a]     = __builtin_amdgcn_mfma_f32_16x16x32_bf16(m0, zf[kk], acc[a],     0, 0, 0);
      acc[a + 1] = __builtin_amdgcn_mfma_f32_16x16x32_bf16(m1, zf[kk], acc[a + 1], 0, 0, 0);
    }
  }

  __syncthreads();    // all waves done reading mu; LDS becomes the output tile

  // write fragments -> LDS [m][c] (fp32, 512B rows, XOR-swizzled to kill the
  // 512B-stride write conflict)
  const int mloc = wid * 16 + l15;    // this lane's m row (D col = l15)
  #pragma unroll
  for (int a = 0; a < 8; ++a) {
    int cb4 = (a * 16 + lq * 4) * 4;  // byte col in the 512B row
    *(f32x4*)(lds + mloc * 512 + (cb4 ^ ((mloc & 7) << 4))) = acc[a];
  }

  // epilogue, batched: gather all 8 transposed rows + a-terms into registers
  // (acc[] is dead, so this fits), then fire the 8 NT stores back-to-back.
  const int hl = lane >> 5;
  const int cg = cbase + l31 * 4;
  f32x4 t[8];
  float av[8];
  #pragma unroll
  for (int i = 0; i < 8; ++i) {
    int m = wid * 16 + i * 2 + hl;
    t[i] = *(const f32x4*)(lds + m * 512 + ((l31 * 16) ^ ((m & 7) << 4)));
    av[i] = atbl[rbase + m];
  }
  if (cg < C_DIM) {                   // divergent only in the last c-tile
    #pragma unroll
    for (int i = 0; i < 8; ++i) {
      int rowg = rbase + wid * 16 + i * 2 + hl;
      f32x4 v;
      #pragma unroll
      for (int r = 0; r < 4; ++r) v[r] = av[i] + btv[r] + t[i][r];
      __builtin_nontemporal_store(v, (f32x4*)(out + (size_t)rowg * C_DIM + cg));
    }
  }
}

extern "C" void kernel_launch(void* const* d_in, const int* in_sizes, int n_in,
                              void* d_out, int out_size, void* d_ws, size_t ws_size,
                              hipStream_t stream) {
  const float* z     = (const float*)d_in[0];
  const float* mu    = (const float*)d_in[1];
  const float* lcov  = (const float*)d_in[2];
  const float* prior = (const float*)d_in[3];
  float* out = (float*)d_out;

  char* w = (char*)d_ws;
  unsigned short* zb  = (unsigned short*)w;                       // 4,194,304 B
  unsigned short* mub = (unsigned short*)(w + 4194304);           // 2,621,440 B
  float* atbl = (float*)(w + 4194304 + 2621440);                  // 65,536 B
  float* btbl = atbl + N_DIM;                                     // 40,960 B
  float* lse  = btbl + C_PAD;                                     // 4 B

  prep_kernel<<<ZPB + MPB + 1, 256, 0, stream>>>(z, mu, lcov, prior,
                                                 zb, mub, atbl, btbl, lse);
  dim3 grid(CT, MT);   // 79 x 256 = 20224 tiles
  lda_main_kernel<<<grid, 256, 0, stream>>>(zb, mub, atbl, btbl, lse, lcov, out);
}

// Round 9
// 128.344 us; speedup vs baseline: 1.5969x; 1.0041x over previous
//
#include <hip/hip_runtime.h>

#define N_DIM 16384
#define C_DIM 10000
#define D_DIM 128
#define CT 79            // c-tiles of 128 (ceil(10000/128))
#define C_PAD 10240      // mu rows padded/zeroed by prep
#define BM 64            // z rows per block tile
#define BN 128           // mu rows per block tile
#define MT 256           // 16384/64 m-tiles
#define ZPB 2048         // z prep blocks  (8 rows each)
#define MPB 1280         // mu prep blocks (8 rows each)

typedef __attribute__((ext_vector_type(8))) short bf16x8;
typedef __attribute__((ext_vector_type(4))) float f32x4;
typedef __attribute__((ext_vector_type(2))) unsigned int uint2v;

static __device__ __forceinline__ unsigned short f2bf(float x) {
  unsigned int u = __float_as_uint(x);
  u += 0x7fffu + ((u >> 16) & 1u);   // round-to-nearest-even
  return (unsigned short)(u >> 16);
}

// --- fused prep, one dispatch (verified R1/R5 version).
// z  -> bf16 LINEAR, pre-scaled by iv=exp(-lc); atbl[n] = -0.5*||z||^2*iv
// mu -> bf16 PRE-SWIZZLED (byte col ^= (row&7)<<4) for main's linear
//       global_load_lds staging (both-sides-or-neither, G21);
//       btbl[c] (lse added in main). last block: lse = logsumexp(prior)
__global__ __launch_bounds__(256) void prep_kernel(
    const float* __restrict__ z, const float* __restrict__ mu,
    const float* __restrict__ log_cov, const float* __restrict__ prior,
    unsigned short* __restrict__ zb, unsigned short* __restrict__ mub,
    float* __restrict__ atbl, float* __restrict__ btbl, float* __restrict__ lse_out) {
  const int bid = blockIdx.x;
  const int tid = threadIdx.x;
  if (bid < ZPB + MPB) {
    const bool isz = bid < ZPB;
    const int lane = tid & 63;
    const int row = (isz ? bid : bid - ZPB) * 8 + ((tid >> 6) << 1) + (lane >> 5);
    const int col = (lane & 31) * 4;      // float index within row
    const int nrows = isz ? N_DIM : C_DIM;
    f32x4 v = {0.f, 0.f, 0.f, 0.f};
    if (row < nrows)
      v = *(const f32x4*)((isz ? z : mu) + (size_t)row * D_DIM + col);
    float ss = v[0]*v[0] + v[1]*v[1] + v[2]*v[2] + v[3]*v[3];
    #pragma unroll
    for (int off = 16; off; off >>= 1) ss += __shfl_down(ss, off, 32);
    float lc = log_cov[0];
    float iv = expf(-lc);
    if (isz) { v[0]*=iv; v[1]*=iv; v[2]*=iv; v[3]*=iv; }   // fold iv into z
    uint2v packed;
    packed[0] = (unsigned int)f2bf(v[0]) | ((unsigned int)f2bf(v[1]) << 16);
    packed[1] = (unsigned int)f2bf(v[2]) | ((unsigned int)f2bf(v[3]) << 16);
    int cb = (lane & 31) * 8;             // byte col of this 8B chunk
    if (isz) {
      *(uint2v*)((char*)zb + (size_t)row * 256 + cb) = packed;               // linear
    } else {
      *(uint2v*)((char*)mub + (size_t)row * 256 + (cb ^ ((row & 7) << 4))) = packed;
    }
    if ((lane & 31) == 0) {
      if (isz) {
        atbl[row] = -0.5f * ss * iv;
      } else {
        btbl[row] = (row < C_DIM)
            ? (prior[row] - 0.5f * ss * iv - 0.5f * (float)D_DIM * lc) : 0.f;
      }
    }
  } else {
    __shared__ float red[256];
    const f32x4* p4 = (const f32x4*)prior;
    float m = -1e30f;
    for (int i = tid; i < C_DIM / 4; i += 256) {
      f32x4 v = p4[i];
      m = fmaxf(fmaxf(fmaxf(m, v[0]), fmaxf(v[1], v[2])), v[3]);
    }
    red[tid] = m; __syncthreads();
    for (int s = 128; s; s >>= 1) {
      if (tid < s) red[tid] = fmaxf(red[tid], red[tid + s]);
      __syncthreads();
    }
    float mx = red[0]; __syncthreads();
    float sum = 0.f;
    for (int i = tid; i < C_DIM / 4; i += 256) {
      f32x4 v = p4[i];
      sum += expf(v[0] - mx) + expf(v[1] - mx) + expf(v[2] - mx) + expf(v[3] - mx);
    }
    red[tid] = sum; __syncthreads();
    for (int s = 128; s; s >>= 1) {
      if (tid < s) red[tid] += red[tid + s];
      __syncthreads();
    }
    if (tid == 0) *lse_out = mx + logf(red[0]);
  }
}

// --- main: the verified best structure (R5, 127.3 us). 64m x 128c tile,
// LDS mu staging via global_load_lds (pre-swizzled source), paired-mf MFMA
// loop (live mf = 2 frags to fit the 102-VGPR / 5-blocks-per-CU budget),
// LDS transpose epilogue with XOR swizzle, nontemporal 512B store runs,
// default block order. Session ledger: LDS staging, transpose epilogue and
// NT stores are all load-bearing (removing any costs 35-100%); occupancy
// 4 vs 5, store-run width, XCD chunking, epilogue batching all neutral or
// worse. ~5.6 TB/s mixed-stream vs 6.8 TB/s pure-fill = practical ceiling.
__global__ __launch_bounds__(256, 5) void lda_main_kernel(
    const unsigned short* __restrict__ zb, const unsigned short* __restrict__ mub,
    const float* __restrict__ atbl, const float* __restrict__ btbl,
    const float* __restrict__ lse_p, const float* __restrict__ log_cov,
    float* __restrict__ out) {
  __shared__ char lds[BN * 256];      // 32 KB (mu tile; later 64x128 f32 out tile)

  const int ct = blockIdx.x;          // 0..78
  const int mt = blockIdx.y;          // 0..255
  const int tid = threadIdx.x;
  const int rbase = mt * BM;
  const int cbase = ct * BN;
  const int wid = tid >> 6;
  const int lane = tid & 63;
  const int l15 = lane & 15;
  const int lq = lane >> 4;

  // stage mu tile: 8 issues x 1KB per wave, linear dest (global pre-swizzled)
  {
    const char* gm = (const char*)mub + (size_t)cbase * 256 + wid * 8192 + lane * 16;
    char* lm = lds + wid * 8192;
    #pragma unroll
    for (int it = 0; it < 8; ++it)
      __builtin_amdgcn_global_load_lds(
          (const __attribute__((address_space(1))) void*)(gm + it * 1024),
          (__attribute__((address_space(3))) void*)(lm + it * 1024), 16, 0, 0);
  }

  // z fragments from global (16KB slab; L1/L2-resident across the block's waves)
  const int zrow = rbase + wid * 16 + l15;     // this lane's z row (MFMA N=col=l15)
  bf16x8 zf[4];
  #pragma unroll
  for (int kk = 0; kk < 4; ++kk)
    zf[kk] = *(const bf16x8*)((const char*)zb + (size_t)zrow * 256 + kk * 64 + lq * 16);

  // per-lane c-terms for the store phase: c = cbase + (lane&31)*4 .. +3
  const int l31 = lane & 31;
  const float lse = lse_p[0];
  f32x4 btv = *(const f32x4*)&btbl[cbase + l31 * 4];
  btv[0] -= lse; btv[1] -= lse; btv[2] -= lse; btv[3] -= lse;

  __syncthreads();    // mu staged

  // MFMA: acc[a] over 8 c-fragments; A=mu (M=c), B=z (N=m).
  // mf loads paired with their MFMAs to cap live mu fragments at 2 (8 VGPR).
  f32x4 acc[8] = {};
  #pragma unroll
  for (int kk = 0; kk < 4; ++kk) {
    const int kbyte = kk * 64 + lq * 16;
    #pragma unroll
    for (int a = 0; a < 8; a += 2) {
      int r0 = a * 16 + l15;
      int r1 = (a + 1) * 16 + l15;
      bf16x8 m0 = *(const bf16x8*)(lds + r0 * 256 + (kbyte ^ ((r0 & 7) << 4)));
      bf16x8 m1 = *(const bf16x8*)(lds + r1 * 256 + (kbyte ^ ((r1 & 7) << 4)));
      acc[a]     = __builtin_amdgcn_mfma_f32_16x16x32_bf16(m0, zf[kk], acc[a],     0, 0, 0);
      acc[a + 1] = __builtin_amdgcn_mfma_f32_16x16x32_bf16(m1, zf[kk], acc[a + 1], 0, 0, 0);
    }
  }

  __syncthreads();    // all waves done reading mu; LDS becomes the output tile

  // write fragments -> LDS [m][c] (fp32, 512B rows, XOR-swizzled to kill the
  // 512B-stride write conflict)
  const int mloc = wid * 16 + l15;    // this lane's m row (D col = l15)
  #pragma unroll
  for (int a = 0; a < 8; ++a) {
    int cb4 = (a * 16 + lq * 4) * 4;  // byte col in the 512B row
    *(f32x4*)(lds + mloc * 512 + (cb4 ^ ((mloc & 7) << 4))) = acc[a];
  }

  // read back row-major (own rows only -- no barrier), 2 rows per instruction,
  // and store 512B contiguous per half-wave (nontemporal: cached stores
  // regress 127->205 by thrashing L2 with the 655MB stream)
  const int hl = lane >> 5;
  #pragma unroll
  for (int i = 0; i < 16; i += 2) {
    int m = wid * 16 + i + hl;
    int rowg = rbase + m;
    f32x4 t = *(const f32x4*)(lds + m * 512 + ((l31 * 16) ^ ((m & 7) << 4)));
    float av = atbl[rowg];
    int cg = cbase + l31 * 4;
    if (cg < C_DIM) {                 // divergent only in the last c-tile
      f32x4 v;
      #pragma unroll
      for (int r = 0; r < 4; ++r) v[r] = av + btv[r] + t[r];
      __builtin_nontemporal_store(v, (f32x4*)(out + (size_t)rowg * C_DIM + cg));
    }
  }
}

extern "C" void kernel_launch(void* const* d_in, const int* in_sizes, int n_in,
                              void* d_out, int out_size, void* d_ws, size_t ws_size,
                              hipStream_t stream) {
  const float* z     = (const float*)d_in[0];
  const float* mu    = (const float*)d_in[1];
  const float* lcov  = (const float*)d_in[2];
  const float* prior = (const float*)d_in[3];
  float* out = (float*)d_out;

  char* w = (char*)d_ws;
  unsigned short* zb  = (unsigned short*)w;                       // 4,194,304 B
  unsigned short* mub = (unsigned short*)(w + 4194304);           // 2,621,440 B
  float* atbl = (float*)(w + 4194304 + 2621440);                  // 65,536 B
  float* btbl = atbl + N_DIM;                                     // 40,960 B
  float* lse  = btbl + C_PAD;                                     // 4 B

  prep_kernel<<<ZPB + MPB + 1, 256, 0, stream>>>(z, mu, lcov, prior,
                                                 zb, mub, atbl, btbl, lse);
  dim3 grid(CT, MT);   // 79 x 256 = 20224 tiles
  lda_main_kernel<<<grid, 256, 0, stream>>>(zb, mub, atbl, btbl, lse, lcov, out);
}